// Round 13
// baseline (41.040 us; speedup 1.0000x reference)
//
#include <hip/hip_runtime.h>

#define NB 16
#define NA 76725
#define NC 8
#define NM 32
#define FEPS 1e-4f
#define TPB 256
#define APB 1024                     // 4 anchors/thread, processed as 2 pairs
#define NBX ((NA + APB - 1) / APB)   // 75 blocks per image

// d_ws: float4 partial[NB*NBX] {cls_sum, reg_sum, npos, cnt} — written every call

__global__ __launch_bounds__(TPB, 4) void focal_main(
    const float* __restrict__ cls_,
    const float* __restrict__ reg_,
    const float* __restrict__ anch_,
    const float* __restrict__ ann_,
    float4* __restrict__ partial)
{
    const int b   = blockIdx.y;
    const int xb  = blockIdx.x;
    const int tid = threadIdx.x;

    const float4* __restrict__ anch4 = reinterpret_cast<const float4*>(anch_);
    const float4* __restrict__ reg4  = reinterpret_cast<const float4*>(reg_);
    const float4* __restrict__ cls4  = reinterpret_cast<const float4*>(cls_);

    const int ab = xb * APB;

    // ---- pair-A loads first: latency overlaps table staging + barrier
    float4 anA[2], rgA[2], c0A[2], c1A[2];
    bool   mkA[2];
    #pragma unroll
    for (int s = 0; s < 2; ++s) {
        const int a = ab + s * TPB + tid;
        mkA[s] = (a < NA);
        const size_t base = (size_t)b * NA + (mkA[s] ? a : (NA - 1));
        anA[s] = anch4[base]; rgA[s] = reg4[base];
        c0A[s] = cls4[base * 2]; c1A[s] = cls4[base * 2 + 1];
    }

    // ---- fused table staging (wave 0 only; 640B of ann_, L2-hot)
    __shared__ float4 s_box[NM];      // {x1,y1,x2+1,y2+1} -> one ds_read_b128/m
    __shared__ float  s_a2[NM], s_lab[NM];
    __shared__ float4 s_epi[NM];
    __shared__ int    s_nvp, s_cnt;
    if (tid < 64) {
        bool valid = false;
        float x1 = 0.f, y1 = 0.f, x2 = 0.f, y2 = 0.f, lab = -1.f;
        if (tid < NM) {
            const float* r = ann_ + ((size_t)b * NM + tid) * 5;
            x1 = r[0]; y1 = r[1]; x2 = r[2]; y2 = r[3]; lab = r[4];
            valid = lab > -0.5f;
        }
        const unsigned long long mask = __ballot(valid);
        const int cnt = __popcll(mask);
        if (tid < NM) {        // sentinel fill first (program order within wave)
            s_box[tid] = make_float4(3e18f, 3e18f, -3e18f, -3e18f);
            s_a2[tid] = 1.f;   s_lab[tid] = -1.f;
            s_epi[tid] = make_float4(0.f, 0.f, 0.f, 0.f);
        }
        if (valid) {           // stable compaction overwrite (later instr wins)
            const int idx = __popcll(mask & ((1ull << tid) - 1ull));
            s_box[idx] = make_float4(x1, y1, x2 + 1.f, y2 + 1.f);
            s_a2[idx] = (x2 - x1 + 1.f) * (y2 - y1 + 1.f);
            s_lab[idx] = lab;
            const float w0 = x2 - x1, h0 = y2 - y1;
            s_epi[idx] = make_float4(x1 + 0.5f * w0, y1 + 0.5f * h0,
                                     __logf(fmaxf(w0, 1.f)), __logf(fmaxf(h0, 1.f)));
        }
        if (tid == 0) { s_nvp = (cnt + 7) & ~7; s_cnt = cnt; }
    }
    __syncthreads();                             // table ready; pair-A drained
    int nvp = __builtin_amdgcn_readfirstlane(s_nvp);

    float cls_c = 0.f, reg_c = 0.f;
    unsigned pos_c = 0;

    // compute a PAIR of anchors: one m-loop (2 LDS issues/m) serves both.
    auto compute_pair = [&](const float4* an, const float4* rg,
                            const float4* cv0, const float4* cv1, const bool* mk) {
        float ax[2], ay[2], az1[2], aw1[2], area1[2], ib[2], ub[2];
        int   arg[2];
        #pragma unroll
        for (int k = 0; k < 2; ++k) {
            ax[k] = an[k].x; ay[k] = an[k].y;
            az1[k] = an[k].z + 1.f; aw1[k] = an[k].w + 1.f;
            area1[k] = (an[k].z - ax[k] + 1.f) * (an[k].w - ay[k] + 1.f);
            ib[k] = 0.f; ub[k] = 1.f; arg[k] = 0;
        }
        #pragma unroll 4
        for (int m = 0; m < nvp; ++m) {
            const float4 q = s_box[m];           // ds_read_b128 broadcast
            const float a2 = s_a2[m];            // ds_read_b32 broadcast
            #pragma unroll
            for (int k = 0; k < 2; ++k) {
                const float w = fminf(az1[k], q.z) - fmaxf(ax[k], q.x);
                const float h = fminf(aw1[k], q.w) - fmaxf(ay[k], q.y);
                const float inter = fmaxf(w, 0.f) * fmaxf(h, 0.f);
                const float u = area1[k] + a2 - inter;
                const bool better = inter * ub[k] > ib[k] * u;  // strict >
                ib[k]  = better ? inter : ib[k];
                ub[k]  = better ? u : ub[k];
                arg[k] = better ? m : arg[k];
            }
        }
        #pragma unroll
        for (int k = 0; k < 2; ++k) {
            const bool pos = ib[k] >= 0.4f * ub[k];
            const bool neg = ib[k] <  0.3f * ub[k];
            const bool act = (pos || neg) && mk[k];
            {
                const float pv[8] = {cv0[k].x, cv0[k].y, cv0[k].z, cv0[k].w,
                                     cv1[k].x, cv1[k].y, cv1[k].z, cv1[k].w};
                float pcl[8];
                float bsum = 0.f;
                #pragma unroll
                for (int c = 0; c < NC; ++c) {
                    const float p = fminf(fmaxf(pv[c], FEPS), 1.f - FEPS);
                    pcl[c] = p;
                    bsum += 0.75f * p * p * (-__logf(1.f - p));
                }
                float contrib = bsum;
                if (pos) {
                    const int labi = (int)s_lab[arg[k]];
                    const float t0 = (labi & 1) ? pcl[1] : pcl[0];
                    const float t1 = (labi & 1) ? pcl[3] : pcl[2];
                    const float t2 = (labi & 1) ? pcl[5] : pcl[4];
                    const float t3 = (labi & 1) ? pcl[7] : pcl[6];
                    const float u0 = (labi & 2) ? t1 : t0;
                    const float u1 = (labi & 2) ? t3 : t2;
                    const float pt = (labi & 4) ? u1 : u0;
                    const float om = 1.f - pt;
                    contrib += 0.25f * om * om * (-__logf(pt))
                             - 0.75f * pt * pt * (-__logf(om));
                }
                cls_c += act ? contrib : 0.f;
            }
            if (pos && mk[k]) {
                pos_c += 1;
                const float4 ep = s_epi[arg[k]];
                const float awd = az1[k] - 1.f - ax[k];
                const float ahd = aw1[k] - 1.f - ay[k];
                const float acx = ax[k] + 0.5f * awd;
                const float acy = ay[k] + 0.5f * ahd;
                const float t0 = __fdividef(ep.x - acx, awd) * 10.f;
                const float t1 = __fdividef(ep.y - acy, ahd) * 10.f;
                const float t2 = (ep.z - __logf(awd)) * 5.f;
                const float t3 = (ep.w - __logf(ahd)) * 5.f;
                const float d0 = fabsf(t0 - rg[k].x);
                const float d1 = fabsf(t1 - rg[k].y);
                const float d2 = fabsf(t2 - rg[k].z);
                const float d3 = fabsf(t3 - rg[k].w);
                auto sl1 = [](float d) {
                    return d <= (1.f / 9.f) ? 4.5f * d * d : d - (0.5f / 9.f);
                };
                reg_c += sl1(d0) + sl1(d1) + sl1(d2) + sl1(d3);
            }
        }
    };

    // ---- software pipeline: prefetch pair B || compute pair A (R11 proven)
    float4 anB[2], rgB[2], c0B[2], c1B[2];
    bool   mkB[2];
    #pragma unroll
    for (int s = 0; s < 2; ++s) {
        const int a = ab + (2 + s) * TPB + tid;
        mkB[s] = (a < NA);
        const size_t base = (size_t)b * NA + (mkB[s] ? a : (NA - 1));
        anB[s] = anch4[base]; rgB[s] = reg4[base];
        c0B[s] = cls4[base * 2]; c1B[s] = cls4[base * 2 + 1];
    }
    __builtin_amdgcn_sched_barrier(0);     // pin prefetch above compute
    compute_pair(anA, rgA, c0A, c1A, mkA);
    compute_pair(anB, rgB, c0B, c1B, mkB);

    // wave-64 shuffle reduction, cross-wave via LDS, one float4 store per block
    #pragma unroll
    for (int off = 32; off > 0; off >>= 1) {
        cls_c += __shfl_down(cls_c, off);
        reg_c += __shfl_down(reg_c, off);
        pos_c += __shfl_down(pos_c, off);
    }
    __shared__ float    sc[4], sr[4];
    __shared__ unsigned sp[4];
    const int wave = tid >> 6, lane = tid & 63;
    if (lane == 0) { sc[wave] = cls_c; sr[wave] = reg_c; sp[wave] = pos_c; }
    __syncthreads();
    if (tid == 0) {
        const float    c = sc[0] + sc[1] + sc[2] + sc[3];
        const float    r = sr[0] + sr[1] + sr[2] + sr[3];
        const unsigned p = sp[0] + sp[1] + sp[2] + sp[3];
        partial[b * NBX + xb] = make_float4(c, r, (float)p, (float)s_cnt);
    }
}

__global__ __launch_bounds__(64) void focal_finalize(
    const float4* __restrict__ partial, float* __restrict__ out)
{
    const int t = threadIdx.x;          // 64 threads
    const int b = t & 15, q = t >> 4;   // 4 strided groups per image
    float cs = 0.f, rs = 0.f, np = 0.f;
    for (int x = q; x < NBX; x += 4) {
        const float4 v = partial[b * NBX + x];
        cs += v.x; rs += v.y; np += v.z;
    }
    cs += __shfl_down(cs, 32); rs += __shfl_down(rs, 32); np += __shfl_down(np, 32);
    cs += __shfl_down(cs, 16); rs += __shfl_down(rs, 16); np += __shfl_down(np, 16);
    float cl = 0.f, rl = 0.f;
    if (t < 16) {
        const float cnt = partial[b * NBX].w;   // num_valid (same for image b)
        cl = cs / fmaxf(np, 1.f);
        rl = (np > 0.5f) ? rs / (np * 4.f) : 0.f;
        if (cnt < 0.5f) { cl = 0.f; rl = 0.f; }
    }
    #pragma unroll
    for (int off = 8; off > 0; off >>= 1) {
        cl += __shfl_down(cl, off);
        rl += __shfl_down(rl, off);
    }
    if (t == 0) {
        out[0] = cl * (1.f / NB);
        out[1] = rl * (1.f / NB);
    }
}

extern "C" void kernel_launch(void* const* d_in, const int* in_sizes, int n_in,
                              void* d_out, int out_size, void* d_ws, size_t ws_size,
                              hipStream_t stream)
{
    const float* cls_  = (const float*)d_in[0];
    const float* reg_  = (const float*)d_in[1];
    const float* anch_ = (const float*)d_in[2];
    const float* ann_  = (const float*)d_in[3];
    float4* partial = (float4*)d_ws;
    float*  out     = (float*)d_out;

    dim3 grid(NBX, NB);
    focal_main<<<grid, dim3(TPB), 0, stream>>>(cls_, reg_, anch_, ann_, partial);
    focal_finalize<<<1, 64, 0, stream>>>(partial, out);
}